// Round 1
// baseline (295.335 us; speedup 1.0000x reference)
//
#include <hip/hip_runtime.h>

// NCC loss (win=21) on vol [B=2, C=1, X=160, Y=192, Z=160] fp32.
// Filter order REORDERED to y -> x -> z so that both STORED passes (P1, P2)
// run along strided axes with lane-contiguous (fully coalesced) accesses, and
// the contiguous-axis (z) filter happens last, fused with cc + reduction, in
// registers (never stored). Intermediates fp8 e4m3 (HW cvt), I^2/J^2 carry a
// x0.25 range-fit scale; P3 unscales x4. 3 graph nodes total (acc/cnt zeroing
// folded into P2, finalize folded into P3 via fence+ticket last-block).

typedef unsigned char u8;
typedef float f2v __attribute__((ext_vector_type(2)));

#define B_   2
#define X_   160
#define Y_   192
#define Z_   160
#define WIN_ 21
#define HALF 10
#define YZ   (Y_ * Z_)                        // 30720
#define NTOT ((size_t)B_ * X_ * Y_ * Z_)      // 9830400 (elements == bytes in fp8)
#define SXN  (B_ * X_)                        // 320

#define YSEG1 12                              // P1: 16 y-segments of 12
#define NSEG1 16
#define XSEG2 40                              // P2: 4 x-segments of 40
#define NSEG2 4

__device__ __forceinline__ uint pack4_fp8(float a, float b, float c, float d)
{
    int u = 0;
    u = __builtin_amdgcn_cvt_pk_fp8_f32(a, b, u, false);
    u = __builtin_amdgcn_cvt_pk_fp8_f32(c, d, u, true);
    return (uint)u;
}

__device__ __forceinline__ float4 unpack4_fp8(uint u)
{
    f2v lo = __builtin_amdgcn_cvt_pk_f32_fp8((int)u, false);
    f2v hi = __builtin_amdgcn_cvt_pk_f32_fp8((int)u, true);
    return make_float4(lo[0], lo[1], hi[0], hi[1]);
}

// guarded row load: row u (stride Z_ floats), zero outside [0, Y_)
__device__ __forceinline__ float4 ld_row_f4(const float* __restrict__ p, int u)
{
    if ((unsigned)u < (unsigned)Y_) return *(const float4*)(p + (size_t)u * Z_);
    return make_float4(0.f, 0.f, 0.f, 0.f);
}

__device__ __forceinline__ void upd_add(float4& W, const float4 v)
{
    W.x += v.x; W.y += v.y; W.z += v.z; W.w += v.w;
}
__device__ __forceinline__ void upd_fma(float4& W, const float4 a, const float4 b)
{
    W.x = fmaf(a.x, b.x, W.x); W.y = fmaf(a.y, b.y, W.y);
    W.z = fmaf(a.z, b.z, W.z); W.w = fmaf(a.w, b.w, W.w);
}
__device__ __forceinline__ void upd_sub2(float4& W, const float4 e, const float4 l)
{
    W.x += e.x - l.x; W.y += e.y - l.y; W.z += e.z - l.z; W.w += e.w - l.w;
}
// W += ea*eb - la*lb (2-fma chain per component)
__device__ __forceinline__ void upd_fms(float4& W, const float4 ea, const float4 eb,
                                        const float4 la, const float4 lb)
{
    W.x = fmaf(ea.x, eb.x, fmaf(-la.x, lb.x, W.x));
    W.y = fmaf(ea.y, eb.y, fmaf(-la.y, lb.y, W.y));
    W.z = fmaf(ea.z, eb.z, fmaf(-la.z, lb.z, W.z));
    W.w = fmaf(ea.w, eb.w, fmaf(-la.w, lb.w, W.w));
}

// ---------------- P1: products + y-filter (coalesced), leave rows re-read ----------------
// thread = (seg, bx, z4). 800 blocks x 256 = 204800 threads = 40 z4 x 320 bx x 16 seg.
__global__ __launch_bounds__(256) void k_prod_yfilt(
    const float* __restrict__ I, const float* __restrict__ J,
    u8* __restrict__ Fy)
{
    int t   = blockIdx.x * 256 + threadIdx.x;
    int zg  = t % 40;                          // z4-group: lanes contiguous in z
    int col = t / 40;                          // [0, 5120)
    int bx  = col % SXN;
    int seg = col / SXN;                       // [0, 16), block-uniform (mostly)
    int y0  = seg * YSEG1;
    const float* Ib = I + (size_t)bx * YZ + zg * 4;
    const float* Jb = J + (size_t)bx * YZ + zg * 4;
    u8* Fb = Fy + (size_t)bx * YZ + zg * 4;

    float4 W0 = make_float4(0.f, 0.f, 0.f, 0.f), W1 = W0, W2 = W0, W3 = W0, W4 = W0;

    // init: window sum over raw rows [y0-10, y0+9] (first output adds y0+10, drops y0-11)
#pragma unroll 4
    for (int k = 0; k < 20; ++k) {
        int u = y0 - 10 + k;
        float4 a = ld_row_f4(Ib, u);
        float4 b = ld_row_f4(Jb, u);
        upd_add(W0, a);
        upd_add(W1, b);
        upd_fma(W2, a, a);
        upd_fma(W3, b, b);
        upd_fma(W4, a, b);
    }

#pragma unroll 2
    for (int r = 0; r < YSEG1; ++r) {
        int y = y0 + r;
        float4 ea = ld_row_f4(Ib, y + 10);     // enter row (guarded)
        float4 eb = ld_row_f4(Jb, y + 10);
        float4 la = ld_row_f4(Ib, y - 11);     // leave row: re-read, L2/L3-hot
        float4 lb = ld_row_f4(Jb, y - 11);
        upd_sub2(W0, ea, la);
        upd_sub2(W1, eb, lb);
        upd_fms(W2, ea, ea, la, la);
        upd_fms(W3, eb, eb, lb, lb);
        upd_fms(W4, ea, eb, la, lb);
        size_t o = (size_t)y * Z_;
        *(uint*)(Fb + o)            = pack4_fp8(W0.x, W0.y, W0.z, W0.w);
        *(uint*)(Fb + NTOT + o)     = pack4_fp8(W1.x, W1.y, W1.z, W1.w);
        *(uint*)(Fb + 2 * NTOT + o) = pack4_fp8(W2.x * 0.25f, W2.y * 0.25f,
                                                W2.z * 0.25f, W2.w * 0.25f);
        *(uint*)(Fb + 3 * NTOT + o) = pack4_fp8(W3.x * 0.25f, W3.y * 0.25f,
                                                W3.z * 0.25f, W3.w * 0.25f);
        *(uint*)(Fb + 4 * NTOT + o) = pack4_fp8(W4.x, W4.y, W4.z, W4.w);
    }
}

// ---------------- P2: x-filter Fy -> H, 21-deep encoded register ring ----------------
template<int X0>
__device__ __forceinline__ void xseg_run(const u8* __restrict__ Fb, u8* __restrict__ Hb)
{
    uint ring[WIN_];
    float W0 = 0.f, W1 = 0.f, W2 = 0.f, W3 = 0.f;

#pragma unroll
    for (int k = 0; k < WIN_; ++k) {           // preload raw x-rows [X0-11, X0+9]
        int r = X0 - 11 + k;                   // static; r <= 129 < X_ always
        uint v = 0u;
        if (r >= 0) v = *(const uint*)(Fb + (size_t)r * YZ);
        ring[k] = v;
        float4 tv = unpack4_fp8(v);
        W0 += tv.x; W1 += tv.y; W2 += tv.z; W3 += tv.w;
    }

#pragma unroll
    for (int g = 0; g < 2; ++g) {
#pragma unroll
        for (int i = 0; i < WIN_; ++i) {
            int step = g * WIN_ + i;           // static
            if (step < XSEG2) {
                int x = X0 + step;
                int xe = x + HALF;
                uint e = 0u;
                if (xe < X_) e = *(const uint*)(Fb + (size_t)xe * YZ);
                float4 te = unpack4_fp8(e);
                float4 tl = unpack4_fp8(ring[i]);  // leaving raw row x-11
                W0 += te.x - tl.x; W1 += te.y - tl.y;
                W2 += te.z - tl.z; W3 += te.w - tl.w;
                ring[i] = e;
                *(uint*)(Hb + (size_t)x * YZ) = pack4_fp8(W0, W1, W2, W3);
            }
        }
    }
}

// 1200 blocks x 256: thread = (c, b, seg, y, z4). c/b/seg uniform per block.
__global__ __launch_bounds__(256) void k_xfilt(const u8* __restrict__ Fy,
                                               u8* __restrict__ H,
                                               double* __restrict__ acc,
                                               unsigned* __restrict__ cnt)
{
    int t = blockIdx.x * 256 + threadIdx.x;    // [0, 307200)
    if (t == 0) { *acc = 0.0; *cnt = 0u; }     // runs before P3 (stream order)
    int zg   = t % 40;
    int y    = (t / 40) % Y_;
    int rest = t / (40 * Y_);                  // [0, 40) = c*8 + b*4 + seg? -> decompose:
    int c    = rest % 5;
    int bs   = rest / 5;                       // [0, 8)
    int b    = bs & 1;
    int seg  = bs >> 1;                        // [0, 4)
    size_t off = (size_t)c * NTOT + (size_t)b * ((size_t)X_ * YZ)
               + (size_t)y * Z_ + zg * 4;
    const u8* Fb = Fy + off;
    u8* Hb = H + off;
    switch (seg) {
        case 0:  xseg_run<0>(Fb, Hb);   break;
        case 1:  xseg_run<40>(Fb, Hb);  break;
        case 2:  xseg_run<80>(Fb, Hb);  break;
        default: xseg_run<120>(Fb, Hb); break;
    }
}

// ---------------- P3: z-filter (in-register) + cc + reduce + finalize ----------------
__device__ __forceinline__ float cc_term(float w0, float w1, float w2, float w3,
                                         float w4, float inv_n)
{
    float cross = fmaf(-(w0 * w1), inv_n, w4);
    float Iv    = fmaf(-(w0 * w0), inv_n, w2 * 4.0f);   // unscale I2 (x0.25 in P1)
    float Jv    = fmaf(-(w1 * w1), inv_n, w3 * 4.0f);   // unscale J2
    float denom = fmaf(Iv, Jv, 1e-5f);
    return (cross * cross) * __builtin_amdgcn_rcpf(denom);
}

// 4800 blocks x 256: thread = (bx, y, z8). 8 outputs/thread, 40 dword loads.
__global__ __launch_bounds__(256) void k_zfilt_cc(const u8* __restrict__ H,
                                                  double* __restrict__ acc,
                                                  unsigned* __restrict__ cnt,
                                                  float* __restrict__ out)
{
    const float inv_n = 1.0f / 9261.0f;        // 21^3
    int t  = blockIdx.x * 256 + threadIdx.x;   // [0, 1228800)
    int zg = t % 20;                           // z8-group
    int y  = (t / 20) % Y_;
    int bx = t / (20 * Y_);                    // [0, 320)
    const u8* base = H + (size_t)bx * YZ + (size_t)y * Z_;
    int u0 = 2 * zg - 3;                       // first dword of the 8-dword window

    float s[5][8];
#pragma unroll
    for (int c = 0; c < 5; ++c) {
        float f[32];                           // z span [z0-12, z0+19], z0 = 8*zg
#pragma unroll
        for (int k = 0; k < 8; ++k) {
            int ui = u0 + k;
            uint q = ((unsigned)ui < 40u)
                   ? *(const uint*)(base + (size_t)c * NTOT + (size_t)(4 * ui))
                   : 0u;
            float4 v = unpack4_fp8(q);
            f[4 * k + 0] = v.x; f[4 * k + 1] = v.y;
            f[4 * k + 2] = v.z; f[4 * k + 3] = v.w;
        }
        float s0 = 0.f;
#pragma unroll
        for (int i = 2; i <= 22; ++i) s0 += f[i];   // window at z0: f[2..22]
        s[c][0] = s0;
#pragma unroll
        for (int r = 1; r < 8; ++r) { s0 += f[r + 22] - f[r + 1]; s[c][r] = s0; }
    }

    float lacc = 0.f;
#pragma unroll
    for (int r = 0; r < 8; ++r)
        lacc += cc_term(s[0][r], s[1][r], s[2][r], s[3][r], s[4][r], inv_n);

#pragma unroll
    for (int off = 32; off > 0; off >>= 1) lacc += __shfl_down(lacc, off);
    __shared__ float wsum[4];
    if ((threadIdx.x & 63) == 0) wsum[threadIdx.x >> 6] = lacc;
    __syncthreads();
    if (threadIdx.x == 0) {
        float sm = (wsum[0] + wsum[1]) + (wsum[2] + wsum[3]);
        atomicAdd(acc, (double)sm);
        __threadfence();
        unsigned old = atomicAdd(cnt, 1u);
        if (old == (unsigned)(gridDim.x - 1)) {          // last block finalizes
            double tot = atomicAdd(acc, 0.0);            // coherent read
            out[0] = 1.0f - (float)(tot / 9830400.0);
        }
    }
}

extern "C" void kernel_launch(void* const* d_in, const int* in_sizes, int n_in,
                              void* d_out, int out_size, void* d_ws, size_t ws_size,
                              hipStream_t stream)
{
    const float* I = (const float*)d_in[0];
    const float* J = (const float*)d_in[1];
    float* out = (float*)d_out;

    char* ws = (char*)d_ws;
    double* acc   = (double*)ws;               // 8 B
    unsigned* cnt = (unsigned*)(ws + 16);      // 4 B
    u8* Fy = (u8*)(ws + 256);                  // 5 x 9.83 MB = 49.2 MB (fp8)
    u8* H  = Fy + 5 * NTOT;                    // 49.2 MB

    k_prod_yfilt<<<dim3(800), 256, 0, stream>>>(I, J, Fy);
    k_xfilt<<<dim3(1200), 256, 0, stream>>>(Fy, H, acc, cnt);
    k_zfilt_cc<<<dim3(4800), 256, 0, stream>>>(H, acc, cnt, out);
}

// Round 3
// 258.463 us; speedup vs baseline: 1.1427x; 1.1427x over previous
//
#include <hip/hip_runtime.h>

// NCC loss (win=21) on vol [B=2, C=1, X=160, Y=192, Z=160] fp32.
// Separable box filters reordered y -> x -> z. P1 (products + y-filter) and
// P2 (x-filter) run along strided axes with lane-contiguous coalesced access;
// P3 stages 16 z-lines x 5 channels into LDS (coalesced global reads), then
// each thread builds its z-window from LDS, computes cc and reduces.
// Intermediates fp8 e4m3 (HW cvt); I^2/J^2 carry x0.25 range-fit scale, P3
// unscales x4. 3 graph nodes (acc/cnt zeroing in P2, finalize ticket in P3).
// NOTE: P3 MUST be launched with TPB3 (=320) threads -- R2's failure was a
// 256-thread launch leaving segments s%8==7 unstaged (NaN from garbage LDS).

typedef unsigned char u8;
typedef float f2v __attribute__((ext_vector_type(2)));

#define B_   2
#define X_   160
#define Y_   192
#define Z_   160
#define WIN_ 21
#define HALF 10
#define YZ   (Y_ * Z_)                        // 30720
#define NTOT ((size_t)B_ * X_ * Y_ * Z_)      // 9830400 (elements == bytes in fp8)
#define SXN  (B_ * X_)                        // 320

#define YSEG1 12                              // P1: 16 y-segments of 12
#define XSEG2 40                              // P2: 4 x-segments of 40

// P3 geometry
#define LINES3 16                             // lines per block
#define TPB3   320                            // threads per block (5 waves)
#define SEGS3  (LINES3 * 5)                   // 80 line-channel segments
#define SEGSTR 47                             // padded LDS stride (dwords): 3 | 40 | 3 | 1

__device__ __forceinline__ uint pack4_fp8(float a, float b, float c, float d)
{
    int u = 0;
    u = __builtin_amdgcn_cvt_pk_fp8_f32(a, b, u, false);
    u = __builtin_amdgcn_cvt_pk_fp8_f32(c, d, u, true);
    return (uint)u;
}

__device__ __forceinline__ float4 unpack4_fp8(uint u)
{
    f2v lo = __builtin_amdgcn_cvt_pk_f32_fp8((int)u, false);
    f2v hi = __builtin_amdgcn_cvt_pk_f32_fp8((int)u, true);
    return make_float4(lo[0], lo[1], hi[0], hi[1]);
}

__device__ __forceinline__ void upd_add(float4& W, const float4 v)
{
    W.x += v.x; W.y += v.y; W.z += v.z; W.w += v.w;
}
__device__ __forceinline__ void upd_fma(float4& W, const float4 a, const float4 b)
{
    W.x = fmaf(a.x, b.x, W.x); W.y = fmaf(a.y, b.y, W.y);
    W.z = fmaf(a.z, b.z, W.z); W.w = fmaf(a.w, b.w, W.w);
}
__device__ __forceinline__ void upd_sub2(float4& W, const float4 e, const float4 l)
{
    W.x += e.x - l.x; W.y += e.y - l.y; W.z += e.z - l.z; W.w += e.w - l.w;
}
__device__ __forceinline__ void upd_fms(float4& W, const float4 ea, const float4 eb,
                                        const float4 la, const float4 lb)
{
    W.x = fmaf(ea.x, eb.x, fmaf(-la.x, lb.x, W.x));
    W.y = fmaf(ea.y, eb.y, fmaf(-la.y, lb.y, W.y));
    W.z = fmaf(ea.z, eb.z, fmaf(-la.z, lb.z, W.z));
    W.w = fmaf(ea.w, eb.w, fmaf(-la.w, lb.w, W.w));
}

// ---------------- P1: products + y-filter, 3-mode template (guard-free interior) ----
#define GNONE 0
#define GLO   1
#define GHI   2

template<int MODE>
__device__ __forceinline__ void yfilt_run(int y0,
                                          const float* __restrict__ Ib,
                                          const float* __restrict__ Jb,
                                          u8* __restrict__ Fb)
{
    const float4 z4 = make_float4(0.f, 0.f, 0.f, 0.f);
    float4 W0 = z4, W1 = z4, W2 = z4, W3 = z4, W4 = z4;

    // init: window sum over raw rows [y0-10, y0+9]
#pragma unroll
    for (int k = 0; k < 20; ++k) {
        int u = y0 - 10 + k;
        float4 a, b;
        if (MODE == GLO) {                     // seg 0 only: u may be < 0
            a = (u >= 0) ? *(const float4*)(Ib + (size_t)u * Z_) : z4;
            b = (u >= 0) ? *(const float4*)(Jb + (size_t)u * Z_) : z4;
        } else {
            a = *(const float4*)(Ib + (size_t)u * Z_);
            b = *(const float4*)(Jb + (size_t)u * Z_);
        }
        upd_add(W0, a);
        upd_add(W1, b);
        upd_fma(W2, a, a);
        upd_fma(W3, b, b);
        upd_fma(W4, a, b);
    }

#pragma unroll
    for (int r = 0; r < YSEG1; ++r) {
        int y  = y0 + r;
        int ye = y + HALF;
        int yl = y - HALF - 1;
        float4 ea, eb, la, lb;
        if (MODE == GHI) {                     // seg 15 only: ye may be >= Y_
            ea = (ye < Y_) ? *(const float4*)(Ib + (size_t)ye * Z_) : z4;
            eb = (ye < Y_) ? *(const float4*)(Jb + (size_t)ye * Z_) : z4;
        } else {
            ea = *(const float4*)(Ib + (size_t)ye * Z_);
            eb = *(const float4*)(Jb + (size_t)ye * Z_);
        }
        if (MODE == GLO) {                     // seg 0 only: yl may be < 0
            la = (yl >= 0) ? *(const float4*)(Ib + (size_t)yl * Z_) : z4;
            lb = (yl >= 0) ? *(const float4*)(Jb + (size_t)yl * Z_) : z4;
        } else {
            la = *(const float4*)(Ib + (size_t)yl * Z_);
            lb = *(const float4*)(Jb + (size_t)yl * Z_);
        }
        upd_sub2(W0, ea, la);
        upd_sub2(W1, eb, lb);
        upd_fms(W2, ea, ea, la, la);
        upd_fms(W3, eb, eb, lb, lb);
        upd_fms(W4, ea, eb, la, lb);
        size_t o = (size_t)y * Z_;
        *(uint*)(Fb + o)            = pack4_fp8(W0.x, W0.y, W0.z, W0.w);
        *(uint*)(Fb + NTOT + o)     = pack4_fp8(W1.x, W1.y, W1.z, W1.w);
        *(uint*)(Fb + 2 * NTOT + o) = pack4_fp8(W2.x * 0.25f, W2.y * 0.25f,
                                                W2.z * 0.25f, W2.w * 0.25f);
        *(uint*)(Fb + 3 * NTOT + o) = pack4_fp8(W3.x * 0.25f, W3.y * 0.25f,
                                                W3.z * 0.25f, W3.w * 0.25f);
        *(uint*)(Fb + 4 * NTOT + o) = pack4_fp8(W4.x, W4.y, W4.z, W4.w);
    }
}

// thread = (seg, bx, z4). 800 blocks x 256 = 204800 = 40 z4 x 320 bx x 16 seg.
// seg uniform per block (12800 threads per seg, 256 | 12800).
__global__ __launch_bounds__(256) void k_prod_yfilt(
    const float* __restrict__ I, const float* __restrict__ J,
    u8* __restrict__ Fy)
{
    int t   = blockIdx.x * 256 + threadIdx.x;
    int zg  = t % 40;
    int col = t / 40;
    int bx  = col % SXN;
    int seg = col / SXN;                       // [0, 16)
    const float* Ib = I + (size_t)bx * YZ + zg * 4;
    const float* Jb = J + (size_t)bx * YZ + zg * 4;
    u8* Fb = Fy + (size_t)bx * YZ + zg * 4;

    if (seg == 0)       yfilt_run<GLO>(0, Ib, Jb, Fb);
    else if (seg == 15) yfilt_run<GHI>(180, Ib, Jb, Fb);
    else                yfilt_run<GNONE>(seg * YSEG1, Ib, Jb, Fb);
}

// ---------------- P2: x-filter Fy -> H, 21-deep encoded register ring ----------------
template<int X0>
__device__ __forceinline__ void xseg_run(const u8* __restrict__ Fb, u8* __restrict__ Hb)
{
    uint ring[WIN_];
    float W0 = 0.f, W1 = 0.f, W2 = 0.f, W3 = 0.f;

#pragma unroll
    for (int k = 0; k < WIN_; ++k) {           // preload raw x-rows [X0-11, X0+9]
        int r = X0 - 11 + k;                   // static; r <= 129 < X_ always
        uint v = 0u;
        if (r >= 0) v = *(const uint*)(Fb + (size_t)r * YZ);
        ring[k] = v;
        float4 tv = unpack4_fp8(v);
        W0 += tv.x; W1 += tv.y; W2 += tv.z; W3 += tv.w;
    }

#pragma unroll
    for (int g = 0; g < 2; ++g) {
#pragma unroll
        for (int i = 0; i < WIN_; ++i) {
            int step = g * WIN_ + i;           // static
            if (step < XSEG2) {
                int x = X0 + step;
                int xe = x + HALF;
                uint e = 0u;
                if (xe < X_) e = *(const uint*)(Fb + (size_t)xe * YZ);
                float4 te = unpack4_fp8(e);
                float4 tl = unpack4_fp8(ring[i]);  // leaving raw row x-11
                W0 += te.x - tl.x; W1 += te.y - tl.y;
                W2 += te.z - tl.z; W3 += te.w - tl.w;
                ring[i] = e;
                *(uint*)(Hb + (size_t)x * YZ) = pack4_fp8(W0, W1, W2, W3);
            }
        }
    }
}

// 1200 blocks x 256: thread = (c, b, seg, y, z4). c/b/seg uniform per block.
__global__ __launch_bounds__(256) void k_xfilt(const u8* __restrict__ Fy,
                                               u8* __restrict__ H,
                                               double* __restrict__ acc,
                                               unsigned* __restrict__ cnt)
{
    int t = blockIdx.x * 256 + threadIdx.x;    // [0, 307200)
    if (t == 0) { *acc = 0.0; *cnt = 0u; }     // runs before P3 (stream order)
    int zg   = t % 40;
    int y    = (t / 40) % Y_;
    int rest = t / (40 * Y_);                  // [0, 40)
    int c    = rest % 5;
    int bs   = rest / 5;                       // [0, 8)
    int b    = bs & 1;
    int seg  = bs >> 1;                        // [0, 4)
    size_t off = (size_t)c * NTOT + (size_t)b * ((size_t)X_ * YZ)
               + (size_t)y * Z_ + zg * 4;
    const u8* Fb = Fy + off;
    u8* Hb = H + off;
    switch (seg) {
        case 0:  xseg_run<0>(Fb, Hb);   break;
        case 1:  xseg_run<40>(Fb, Hb);  break;
        case 2:  xseg_run<80>(Fb, Hb);  break;
        default: xseg_run<120>(Fb, Hb); break;
    }
}

// ---------------- P3: LDS-staged z-filter + cc + reduce + finalize ----------------
__device__ __forceinline__ float cc_term(float w0, float w1, float w2, float w3,
                                         float w4, float inv_n)
{
    float cross = fmaf(-(w0 * w1), inv_n, w4);
    float Iv    = fmaf(-(w0 * w0), inv_n, w2 * 4.0f);   // unscale I2 (x0.25 in P1)
    float Jv    = fmaf(-(w1 * w1), inv_n, w3 * 4.0f);   // unscale J2
    float denom = fmaf(Iv, Jv, 1e-5f);
    return (cross * cross) * __builtin_amdgcn_rcpf(denom);
}

// 3840 blocks x TPB3=320: block stages LINES3=16 lines x 5 ch into LDS
// (coalesced), then thread = (line, zg) computes 8 z-outputs from LDS.
// Global line L = bx*Y_ + y, base = H + L*Z_ (+ c*NTOT per channel).
__global__ __launch_bounds__(TPB3) void k_zfilt_cc(const u8* __restrict__ H,
                                                   double* __restrict__ acc,
                                                   unsigned* __restrict__ cnt,
                                                   float* __restrict__ out)
{
    const float inv_n = 1.0f / 9261.0f;        // 21^3
    __shared__ uint lds[SEGS3 * SEGSTR];       // 80 * 47 * 4 = 15040 B
    int tid = threadIdx.x;
    int L0  = blockIdx.x * LINES3;             // first global line of this block

    // zero the 3-dword margins of each segment (window reach is [-3, +3] dwords)
    if (tid < SEGS3) {
        int o = tid * SEGSTR;
        lds[o + 0] = 0u; lds[o + 1] = 0u; lds[o + 2] = 0u;
        lds[o + 43] = 0u; lds[o + 44] = 0u; lds[o + 45] = 0u;
    }

    // coalesced stage: lanes 0..39 read one contiguous 160-B segment
    int dw    = tid % 40;
    int sBase = tid / 40;                      // [0, 8)
#pragma unroll
    for (int it = 0; it < 10; ++it) {
        int s    = sBase + 8 * it;             // [0, 80)
        int line = s / 5;
        int c    = s % 5;
        uint v = *(const uint*)(H + (size_t)(L0 + line) * Z_
                                  + (size_t)c * NTOT + (size_t)(4 * dw));
        lds[s * SEGSTR + 3 + dw] = v;
    }
    __syncthreads();

    // compute: thread = (line, zg), 8 z outputs, window from LDS (no guards)
    int line = tid / 20;
    int zg   = tid % 20;                       // z0 = 8*zg
    int u0   = 2 * zg - 3;                     // first dword of the 8-dword window

    float s5[5][8];
#pragma unroll
    for (int c = 0; c < 5; ++c) {
        int la = (line * 5 + c) * SEGSTR + 3 + u0;   // pads make la+k always valid
        float f[32];                           // z span [z0-12, z0+19]
#pragma unroll
        for (int k = 0; k < 8; ++k) {
            float4 v = unpack4_fp8(lds[la + k]);
            f[4 * k + 0] = v.x; f[4 * k + 1] = v.y;
            f[4 * k + 2] = v.z; f[4 * k + 3] = v.w;
        }
        float s0 = 0.f;
#pragma unroll
        for (int i = 2; i <= 22; ++i) s0 += f[i];   // window at z0: f[2..22]
        s5[c][0] = s0;
#pragma unroll
        for (int r = 1; r < 8; ++r) { s0 += f[r + 22] - f[r + 1]; s5[c][r] = s0; }
    }

    float lacc = 0.f;
#pragma unroll
    for (int r = 0; r < 8; ++r)
        lacc += cc_term(s5[0][r], s5[1][r], s5[2][r], s5[3][r], s5[4][r], inv_n);

#pragma unroll
    for (int off = 32; off > 0; off >>= 1) lacc += __shfl_down(lacc, off);
    __shared__ float wsum[TPB3 / 64];
    if ((tid & 63) == 0) wsum[tid >> 6] = lacc;
    __syncthreads();
    if (tid == 0) {
        float sm = 0.f;
#pragma unroll
        for (int w = 0; w < TPB3 / 64; ++w) sm += wsum[w];
        atomicAdd(acc, (double)sm);
        __threadfence();
        unsigned old = atomicAdd(cnt, 1u);
        if (old == (unsigned)(gridDim.x - 1)) {          // last block finalizes
            double tot = atomicAdd(acc, 0.0);            // coherent read
            out[0] = 1.0f - (float)(tot / 9830400.0);
        }
    }
}

extern "C" void kernel_launch(void* const* d_in, const int* in_sizes, int n_in,
                              void* d_out, int out_size, void* d_ws, size_t ws_size,
                              hipStream_t stream)
{
    const float* I = (const float*)d_in[0];
    const float* J = (const float*)d_in[1];
    float* out = (float*)d_out;

    char* ws = (char*)d_ws;
    double* acc   = (double*)ws;               // 8 B
    unsigned* cnt = (unsigned*)(ws + 16);      // 4 B
    u8* Fy = (u8*)(ws + 256);                  // 5 x 9.83 MB = 49.2 MB (fp8)
    u8* H  = Fy + 5 * NTOT;                    // 49.2 MB

    k_prod_yfilt<<<dim3(800), 256, 0, stream>>>(I, J, Fy);
    k_xfilt<<<dim3(1200), 256, 0, stream>>>(Fy, H, acc, cnt);
    k_zfilt_cc<<<dim3(3840), TPB3, 0, stream>>>(H, acc, cnt, out);
}

// Round 4
// 163.437 us; speedup vs baseline: 1.8070x; 1.5814x over previous
//
#include <hip/hip_runtime.h>

// NCC loss (win=21) on vol [B=2, C=1, X=160, Y=192, Z=160] fp32.
// Separable box filters reordered y -> x -> z. P1 (products + y-filter) and
// P2 (x-filter) run along strided axes with lane-contiguous coalesced access;
// P3 stages 16 z-lines x 5 channels into LDS (coalesced global reads), builds
// z-windows from LDS, computes cc, and PLAIN-STORES one partial double per
// block (NO atomics / NO threadfence -- R3 showed the same-address f64 atomic
// + device fence + ticket serialized the kernel at ~31 ns/block). P4 (1 block)
// sums the 3840 partials and finalizes. Intermediates fp8 e4m3 (HW cvt);
// I^2/J^2 carry x0.25 range-fit scale, P3 unscales x4.

typedef unsigned char u8;
typedef float f2v __attribute__((ext_vector_type(2)));

#define B_   2
#define X_   160
#define Y_   192
#define Z_   160
#define WIN_ 21
#define HALF 10
#define YZ   (Y_ * Z_)                        // 30720
#define NTOT ((size_t)B_ * X_ * Y_ * Z_)      // 9830400 (elements == bytes in fp8)
#define SXN  (B_ * X_)                        // 320

#define YSEG1 12                              // P1: 16 y-segments of 12
#define XSEG2 40                              // P2: 4 x-segments of 40

// P3 geometry
#define LINES3 16                             // lines per block
#define TPB3   320                            // threads per block (5 waves)
#define SEGS3  (LINES3 * 5)                   // 80 line-channel segments
#define SEGSTR 47                             // padded LDS stride (dwords): 3 | 40 | 3 | 1
#define NBLK3  3840                           // (B_*X_*Y_)/LINES3

__device__ __forceinline__ uint pack4_fp8(float a, float b, float c, float d)
{
    int u = 0;
    u = __builtin_amdgcn_cvt_pk_fp8_f32(a, b, u, false);
    u = __builtin_amdgcn_cvt_pk_fp8_f32(c, d, u, true);
    return (uint)u;
}

__device__ __forceinline__ float4 unpack4_fp8(uint u)
{
    f2v lo = __builtin_amdgcn_cvt_pk_f32_fp8((int)u, false);
    f2v hi = __builtin_amdgcn_cvt_pk_f32_fp8((int)u, true);
    return make_float4(lo[0], lo[1], hi[0], hi[1]);
}

__device__ __forceinline__ void upd_add(float4& W, const float4 v)
{
    W.x += v.x; W.y += v.y; W.z += v.z; W.w += v.w;
}
__device__ __forceinline__ void upd_fma(float4& W, const float4 a, const float4 b)
{
    W.x = fmaf(a.x, b.x, W.x); W.y = fmaf(a.y, b.y, W.y);
    W.z = fmaf(a.z, b.z, W.z); W.w = fmaf(a.w, b.w, W.w);
}
__device__ __forceinline__ void upd_sub2(float4& W, const float4 e, const float4 l)
{
    W.x += e.x - l.x; W.y += e.y - l.y; W.z += e.z - l.z; W.w += e.w - l.w;
}
__device__ __forceinline__ void upd_fms(float4& W, const float4 ea, const float4 eb,
                                        const float4 la, const float4 lb)
{
    W.x = fmaf(ea.x, eb.x, fmaf(-la.x, lb.x, W.x));
    W.y = fmaf(ea.y, eb.y, fmaf(-la.y, lb.y, W.y));
    W.z = fmaf(ea.z, eb.z, fmaf(-la.z, lb.z, W.z));
    W.w = fmaf(ea.w, eb.w, fmaf(-la.w, lb.w, W.w));
}

// ---------------- P1: products + y-filter, 3-mode template (guard-free interior) ----
#define GNONE 0
#define GLO   1
#define GHI   2

template<int MODE>
__device__ __forceinline__ void yfilt_run(int y0,
                                          const float* __restrict__ Ib,
                                          const float* __restrict__ Jb,
                                          u8* __restrict__ Fb)
{
    const float4 z4 = make_float4(0.f, 0.f, 0.f, 0.f);
    float4 W0 = z4, W1 = z4, W2 = z4, W3 = z4, W4 = z4;

    // init: window sum over raw rows [y0-10, y0+9]
#pragma unroll
    for (int k = 0; k < 20; ++k) {
        int u = y0 - 10 + k;
        float4 a, b;
        if (MODE == GLO) {                     // seg 0 only: u may be < 0
            a = (u >= 0) ? *(const float4*)(Ib + (size_t)u * Z_) : z4;
            b = (u >= 0) ? *(const float4*)(Jb + (size_t)u * Z_) : z4;
        } else {
            a = *(const float4*)(Ib + (size_t)u * Z_);
            b = *(const float4*)(Jb + (size_t)u * Z_);
        }
        upd_add(W0, a);
        upd_add(W1, b);
        upd_fma(W2, a, a);
        upd_fma(W3, b, b);
        upd_fma(W4, a, b);
    }

#pragma unroll
    for (int r = 0; r < YSEG1; ++r) {
        int y  = y0 + r;
        int ye = y + HALF;
        int yl = y - HALF - 1;
        float4 ea, eb, la, lb;
        if (MODE == GHI) {                     // seg 15 only: ye may be >= Y_
            ea = (ye < Y_) ? *(const float4*)(Ib + (size_t)ye * Z_) : z4;
            eb = (ye < Y_) ? *(const float4*)(Jb + (size_t)ye * Z_) : z4;
        } else {
            ea = *(const float4*)(Ib + (size_t)ye * Z_);
            eb = *(const float4*)(Jb + (size_t)ye * Z_);
        }
        if (MODE == GLO) {                     // seg 0 only: yl may be < 0
            la = (yl >= 0) ? *(const float4*)(Ib + (size_t)yl * Z_) : z4;
            lb = (yl >= 0) ? *(const float4*)(Jb + (size_t)yl * Z_) : z4;
        } else {
            la = *(const float4*)(Ib + (size_t)yl * Z_);
            lb = *(const float4*)(Jb + (size_t)yl * Z_);
        }
        upd_sub2(W0, ea, la);
        upd_sub2(W1, eb, lb);
        upd_fms(W2, ea, ea, la, la);
        upd_fms(W3, eb, eb, lb, lb);
        upd_fms(W4, ea, eb, la, lb);
        size_t o = (size_t)y * Z_;
        *(uint*)(Fb + o)            = pack4_fp8(W0.x, W0.y, W0.z, W0.w);
        *(uint*)(Fb + NTOT + o)     = pack4_fp8(W1.x, W1.y, W1.z, W1.w);
        *(uint*)(Fb + 2 * NTOT + o) = pack4_fp8(W2.x * 0.25f, W2.y * 0.25f,
                                                W2.z * 0.25f, W2.w * 0.25f);
        *(uint*)(Fb + 3 * NTOT + o) = pack4_fp8(W3.x * 0.25f, W3.y * 0.25f,
                                                W3.z * 0.25f, W3.w * 0.25f);
        *(uint*)(Fb + 4 * NTOT + o) = pack4_fp8(W4.x, W4.y, W4.z, W4.w);
    }
}

// thread = (seg, bx, z4). 800 blocks x 256 = 204800 = 40 z4 x 320 bx x 16 seg.
__global__ __launch_bounds__(256) void k_prod_yfilt(
    const float* __restrict__ I, const float* __restrict__ J,
    u8* __restrict__ Fy)
{
    int t   = blockIdx.x * 256 + threadIdx.x;
    int zg  = t % 40;
    int col = t / 40;
    int bx  = col % SXN;
    int seg = col / SXN;                       // [0, 16)
    const float* Ib = I + (size_t)bx * YZ + zg * 4;
    const float* Jb = J + (size_t)bx * YZ + zg * 4;
    u8* Fb = Fy + (size_t)bx * YZ + zg * 4;

    if (seg == 0)       yfilt_run<GLO>(0, Ib, Jb, Fb);
    else if (seg == 15) yfilt_run<GHI>(180, Ib, Jb, Fb);
    else                yfilt_run<GNONE>(seg * YSEG1, Ib, Jb, Fb);
}

// ---------------- P2: x-filter Fy -> H, 21-deep encoded register ring ----------------
template<int X0>
__device__ __forceinline__ void xseg_run(const u8* __restrict__ Fb, u8* __restrict__ Hb)
{
    uint ring[WIN_];
    float W0 = 0.f, W1 = 0.f, W2 = 0.f, W3 = 0.f;

#pragma unroll
    for (int k = 0; k < WIN_; ++k) {           // preload raw x-rows [X0-11, X0+9]
        int r = X0 - 11 + k;                   // static; r <= 129 < X_ always
        uint v = 0u;
        if (r >= 0) v = *(const uint*)(Fb + (size_t)r * YZ);
        ring[k] = v;
        float4 tv = unpack4_fp8(v);
        W0 += tv.x; W1 += tv.y; W2 += tv.z; W3 += tv.w;
    }

#pragma unroll
    for (int g = 0; g < 2; ++g) {
#pragma unroll
        for (int i = 0; i < WIN_; ++i) {
            int step = g * WIN_ + i;           // static
            if (step < XSEG2) {
                int x = X0 + step;
                int xe = x + HALF;
                uint e = 0u;
                if (xe < X_) e = *(const uint*)(Fb + (size_t)xe * YZ);
                float4 te = unpack4_fp8(e);
                float4 tl = unpack4_fp8(ring[i]);  // leaving raw row x-11
                W0 += te.x - tl.x; W1 += te.y - tl.y;
                W2 += te.z - tl.z; W3 += te.w - tl.w;
                ring[i] = e;
                *(uint*)(Hb + (size_t)x * YZ) = pack4_fp8(W0, W1, W2, W3);
            }
        }
    }
}

// 1200 blocks x 256: thread = (c, b, seg, y, z4). c/b/seg uniform per block.
__global__ __launch_bounds__(256) void k_xfilt(const u8* __restrict__ Fy,
                                               u8* __restrict__ H)
{
    int t = blockIdx.x * 256 + threadIdx.x;    // [0, 307200)
    int zg   = t % 40;
    int y    = (t / 40) % Y_;
    int rest = t / (40 * Y_);                  // [0, 40)
    int c    = rest % 5;
    int bs   = rest / 5;                       // [0, 8)
    int b    = bs & 1;
    int seg  = bs >> 1;                        // [0, 4)
    size_t off = (size_t)c * NTOT + (size_t)b * ((size_t)X_ * YZ)
               + (size_t)y * Z_ + zg * 4;
    const u8* Fb = Fy + off;
    u8* Hb = H + off;
    switch (seg) {
        case 0:  xseg_run<0>(Fb, Hb);   break;
        case 1:  xseg_run<40>(Fb, Hb);  break;
        case 2:  xseg_run<80>(Fb, Hb);  break;
        default: xseg_run<120>(Fb, Hb); break;
    }
}

// ---------------- P3: LDS-staged z-filter + cc + per-block partial store ------------
__device__ __forceinline__ float cc_term(float w0, float w1, float w2, float w3,
                                         float w4, float inv_n)
{
    float cross = fmaf(-(w0 * w1), inv_n, w4);
    float Iv    = fmaf(-(w0 * w0), inv_n, w2 * 4.0f);   // unscale I2 (x0.25 in P1)
    float Jv    = fmaf(-(w1 * w1), inv_n, w3 * 4.0f);   // unscale J2
    float denom = fmaf(Iv, Jv, 1e-5f);
    return (cross * cross) * __builtin_amdgcn_rcpf(denom);
}

// NBLK3=3840 blocks x TPB3=320: block stages LINES3=16 lines x 5 ch into LDS
// (coalesced), thread = (line, zg) computes 8 z-outputs from LDS, block-reduces
// and plain-stores one double to part[bid]. NO atomics, NO fence.
__global__ __launch_bounds__(TPB3) void k_zfilt_cc(const u8* __restrict__ H,
                                                   double* __restrict__ part)
{
    const float inv_n = 1.0f / 9261.0f;        // 21^3
    __shared__ uint lds[SEGS3 * SEGSTR];       // 80 * 47 * 4 = 15040 B
    int tid = threadIdx.x;
    int L0  = blockIdx.x * LINES3;             // first global line of this block

    // zero the 3-dword margins of each segment (window reach is [-3, +3] dwords)
    if (tid < SEGS3) {
        int o = tid * SEGSTR;
        lds[o + 0] = 0u; lds[o + 1] = 0u; lds[o + 2] = 0u;
        lds[o + 43] = 0u; lds[o + 44] = 0u; lds[o + 45] = 0u;
    }

    // coalesced stage: lanes 0..39 read one contiguous 160-B segment
    int dw    = tid % 40;
    int sBase = tid / 40;                      // [0, 8)
#pragma unroll
    for (int it = 0; it < 10; ++it) {
        int s    = sBase + 8 * it;             // [0, 80)
        int line = s / 5;
        int c    = s % 5;
        uint v = *(const uint*)(H + (size_t)(L0 + line) * Z_
                                  + (size_t)c * NTOT + (size_t)(4 * dw));
        lds[s * SEGSTR + 3 + dw] = v;
    }
    __syncthreads();

    // compute: thread = (line, zg), 8 z outputs, window from LDS (no guards)
    int line = tid / 20;
    int zg   = tid % 20;                       // z0 = 8*zg
    int u0   = 2 * zg - 3;                     // first dword of the 8-dword window

    float s5[5][8];
#pragma unroll
    for (int c = 0; c < 5; ++c) {
        int la = (line * 5 + c) * SEGSTR + 3 + u0;   // pads make la+k always valid
        float f[32];                           // z span [z0-12, z0+19]
#pragma unroll
        for (int k = 0; k < 8; ++k) {
            float4 v = unpack4_fp8(lds[la + k]);
            f[4 * k + 0] = v.x; f[4 * k + 1] = v.y;
            f[4 * k + 2] = v.z; f[4 * k + 3] = v.w;
        }
        float s0 = 0.f;
#pragma unroll
        for (int i = 2; i <= 22; ++i) s0 += f[i];   // window at z0: f[2..22]
        s5[c][0] = s0;
#pragma unroll
        for (int r = 1; r < 8; ++r) { s0 += f[r + 22] - f[r + 1]; s5[c][r] = s0; }
    }

    float lacc = 0.f;
#pragma unroll
    for (int r = 0; r < 8; ++r)
        lacc += cc_term(s5[0][r], s5[1][r], s5[2][r], s5[3][r], s5[4][r], inv_n);

#pragma unroll
    for (int off = 32; off > 0; off >>= 1) lacc += __shfl_down(lacc, off);
    __shared__ float wsum[TPB3 / 64];
    if ((tid & 63) == 0) wsum[tid >> 6] = lacc;
    __syncthreads();
    if (tid == 0) {
        float sm = 0.f;
#pragma unroll
        for (int w = 0; w < TPB3 / 64; ++w) sm += wsum[w];
        part[blockIdx.x] = (double)sm;         // plain store; kernel boundary orders it
    }
}

// ---------------- P4: sum 3840 partials + finalize ----------------
__global__ __launch_bounds__(256) void k_final4(const double* __restrict__ part,
                                                float* __restrict__ out)
{
    int tid = threadIdx.x;
    double s = 0.0;
#pragma unroll
    for (int k = 0; k < NBLK3 / 256; ++k)      // 15 each
        s += part[tid + 256 * k];
#pragma unroll
    for (int off = 32; off > 0; off >>= 1) s += __shfl_down(s, off);
    __shared__ double wsum[4];
    if ((tid & 63) == 0) wsum[tid >> 6] = s;
    __syncthreads();
    if (tid == 0) {
        double tot = (wsum[0] + wsum[1]) + (wsum[2] + wsum[3]);
        out[0] = 1.0f - (float)(tot / 9830400.0);
    }
}

extern "C" void kernel_launch(void* const* d_in, const int* in_sizes, int n_in,
                              void* d_out, int out_size, void* d_ws, size_t ws_size,
                              hipStream_t stream)
{
    const float* I = (const float*)d_in[0];
    const float* J = (const float*)d_in[1];
    float* out = (float*)d_out;

    char* ws = (char*)d_ws;
    double* part = (double*)ws;                // 3840 doubles = 30 KB
    u8* Fy = (u8*)(ws + 32768);                // 5 x 9.83 MB = 49.2 MB (fp8)
    u8* H  = Fy + 5 * NTOT;                    // 49.2 MB

    k_prod_yfilt<<<dim3(800), 256, 0, stream>>>(I, J, Fy);
    k_xfilt<<<dim3(1200), 256, 0, stream>>>(Fy, H);
    k_zfilt_cc<<<dim3(NBLK3), TPB3, 0, stream>>>(H, part);
    k_final4<<<dim3(1), 256, 0, stream>>>(part, out);
}